// Round 1
// baseline (477.062 us; speedup 1.0000x reference)
//
#include <hip/hip_runtime.h>
#include <math.h>

typedef __bf16 bf16_t;
typedef __bf16 bf16x8 __attribute__((ext_vector_type(8)));
typedef float f32x4 __attribute__((ext_vector_type(4)));

// ---------------------------------------------------------------------------
// fp32 -> bf16 convert (vectorized 8/thread)
// ---------------------------------------------------------------------------
__global__ __launch_bounds__(256) void cvt_f32_to_bf16(const float* __restrict__ in,
                                                       bf16_t* __restrict__ out, int n8) {
    int i = blockIdx.x * 256 + threadIdx.x;
    if (i >= n8) return;
    const float4* p = (const float4*)in + (size_t)i * 2;
    float4 a = p[0], b = p[1];
    union { bf16_t h[8]; uint4 u; } pk;
    pk.h[0] = (bf16_t)a.x; pk.h[1] = (bf16_t)a.y; pk.h[2] = (bf16_t)a.z; pk.h[3] = (bf16_t)a.w;
    pk.h[4] = (bf16_t)b.x; pk.h[5] = (bf16_t)b.y; pk.h[6] = (bf16_t)b.z; pk.h[7] = (bf16_t)b.w;
    ((uint4*)out)[i] = pk.u;
}

// ---------------------------------------------------------------------------
// GEMM core: C[M,N] = A[M,K] @ B[N,K]^T (+bias), bf16 in, OutT out.
// 128x128 tile, BK=32, 256 threads = 4 waves (2x2 of 64x64), 16x16x32 MFMA.
// ---------------------------------------------------------------------------
template <typename OutT>
__device__ __forceinline__ void gemm_core(const bf16_t* __restrict__ A,
                                          const bf16_t* __restrict__ Bm,
                                          const float* __restrict__ bias,
                                          OutT* __restrict__ C, int M, int N, int K) {
    __shared__ __align__(16) bf16_t As[128 * 32];
    __shared__ __align__(16) bf16_t Bs[128 * 32];
    const int tid = threadIdx.x;
    const int l = tid & 63, w = tid >> 6;
    const int l16 = l & 15, lg = l >> 4;
    const int wm = w >> 1, wn = w & 1;
    const int m0 = blockIdx.x * 128, n0 = blockIdx.y * 128;

    f32x4 acc[4][4] = {};  // [mf][nf], zero-init

    for (int k0 = 0; k0 < K; k0 += 32) {
        __syncthreads();
#pragma unroll
        for (int j = 0; j < 2; ++j) {  // stage A,B tiles: 512 16B-chunks each / 256 thr
            int chunk = tid + j * 256;
            int r = chunk >> 2, c = chunk & 3;  // row, k-chunk(8 elems)
            *(uint4*)&As[chunk * 8] = *(const uint4*)(A + (size_t)(m0 + r) * K + k0 + c * 8);
            *(uint4*)&Bs[chunk * 8] = *(const uint4*)(Bm + (size_t)(n0 + r) * K + k0 + c * 8);
        }
        __syncthreads();
        bf16x8 af[4], bfr[4];
#pragma unroll
        for (int i = 0; i < 4; ++i) {  // A-frag: row=l16, k=lg*8..+7
            af[i]  = *(const bf16x8*)&As[(wm * 64 + i * 16 + l16) * 32 + lg * 8];
            bfr[i] = *(const bf16x8*)&Bs[(wn * 64 + i * 16 + l16) * 32 + lg * 8];
        }
#pragma unroll
        for (int mf = 0; mf < 4; ++mf)
#pragma unroll
            for (int nf = 0; nf < 4; ++nf)
                acc[mf][nf] = __builtin_amdgcn_mfma_f32_16x16x32_bf16(af[mf], bfr[nf], acc[mf][nf], 0, 0, 0);
    }
    // epilogue: C/D layout row=lg*4+r, col=l16
#pragma unroll
    for (int mf = 0; mf < 4; ++mf) {
#pragma unroll
        for (int nf = 0; nf < 4; ++nf) {
            int col = n0 + wn * 64 + nf * 16 + l16;
            float bv = bias ? bias[col] : 0.f;
#pragma unroll
            for (int r = 0; r < 4; ++r) {
                int row = m0 + wm * 64 + mf * 16 + lg * 4 + r;
                C[(size_t)row * N + col] = (OutT)(acc[mf][nf][r] + bv);
            }
        }
    }
}

__global__ __launch_bounds__(256) void gemm_qkv(const bf16_t* __restrict__ A,
                                                const bf16_t* __restrict__ W0,
                                                const bf16_t* __restrict__ W1,
                                                const bf16_t* __restrict__ W2,
                                                bf16_t* __restrict__ O0, bf16_t* __restrict__ O1,
                                                bf16_t* __restrict__ O2, int M, int N, int K) {
    const bf16_t* Bm = (blockIdx.z == 0) ? W0 : (blockIdx.z == 1) ? W1 : W2;
    bf16_t* C = (blockIdx.z == 0) ? O0 : (blockIdx.z == 1) ? O1 : O2;
    gemm_core<bf16_t>(A, Bm, nullptr, C, M, N, K);
}

__global__ __launch_bounds__(256) void gemm_bias_f32(const bf16_t* __restrict__ A,
                                                     const bf16_t* __restrict__ Bm,
                                                     const float* __restrict__ bias,
                                                     float* __restrict__ C, int M, int N, int K) {
    gemm_core<float>(A, Bm, bias, C, M, N, K);
}

// ---------------------------------------------------------------------------
// V transpose: [B*S, D] -> [B, H, 128, S]  (64x64 LDS tiles)
// ---------------------------------------------------------------------------
__global__ __launch_bounds__(256) void transpose_v(const bf16_t* __restrict__ V,
                                                   bf16_t* __restrict__ Vt, int S, int H, int Bn) {
    __shared__ bf16_t t[64][72];  // 72*2=144B row stride, keeps 16B alignment
    const int s0 = blockIdx.x * 64, d0 = blockIdx.y * 64, b = blockIdx.z;
    const int D = H * 128;
    const int tid = threadIdx.x;
#pragma unroll
    for (int j = 0; j < 2; ++j) {
        int chunk = tid + j * 256;
        int r = chunk >> 3, c8 = chunk & 7;
        *(uint4*)&t[r][c8 * 8] = *(const uint4*)(V + (size_t)(b * S + s0 + r) * D + d0 + c8 * 8);
    }
    __syncthreads();
#pragma unroll
    for (int j = 0; j < 2; ++j) {
        int chunk = tid + j * 256;
        int rr = chunk >> 3, cc = chunk & 7;  // rr: d-row, cc: s-chunk
        union { bf16_t h[8]; uint4 u; } pk;
#pragma unroll
        for (int u = 0; u < 8; ++u) pk.h[u] = t[cc * 8 + u][rr];
        int dg = d0 + rr;
        size_t idx = ((size_t)(b * H + (dg >> 7)) * 128 + (dg & 127)) * S + s0 + cc * 8;
        *(uint4*)&Vt[idx] = pk.u;
    }
}

// ---------------------------------------------------------------------------
// Flash attention fwd, causal. 256 thr = 4 waves, each wave: 16 q-rows.
// Q-tile 64, K-tile 64, HD=128. Q in regs; K/V^T/P in LDS (XOR chunk-swizzled:
// row strides are 256B/128B/128B == 0 mod bank period -> must swizzle).
// ---------------------------------------------------------------------------
__global__ __launch_bounds__(256) void attn_fwd(const bf16_t* __restrict__ Q,
                                                const bf16_t* __restrict__ Kk,
                                                const bf16_t* __restrict__ Vt,
                                                bf16_t* __restrict__ Ctx, int Bn, int S, int H) {
    const int HDc = 128;
    const int D = H * HDc;
    const int qt = blockIdx.x, q0 = qt * 64;
    const int bh = blockIdx.y;
    const int b = bh / H, h = bh - b * H;
    const int tid = threadIdx.x;
    const int w = tid >> 6, l = tid & 63;
    const int l16 = l & 15, lg = l >> 4;

    __shared__ __align__(16) bf16_t ks[64 * 128];    // [key][d], swizzled 16B chunks
    __shared__ __align__(16) bf16_t vs[128 * 64];    // [d][key], swizzled
    __shared__ __align__(16) bf16_t ps[4][16 * 64];  // per-wave P, swizzled

    const float scale = 0.08838834764831845f;  // 1/sqrt(128)

    // Q A-frags: row=l16 (wave q-row), k(d)=d4*32+lg*8
    bf16x8 qf[4];
    {
        const bf16_t* qp = Q + (size_t)(b * S + q0 + w * 16 + l16) * D + h * HDc + lg * 8;
#pragma unroll
        for (int d4 = 0; d4 < 4; ++d4) qf[d4] = *(const bf16x8*)(qp + d4 * 32);
    }

    const f32x4 zero4 = {0.f, 0.f, 0.f, 0.f};
    f32x4 ctx[8];
#pragma unroll
    for (int f = 0; f < 8; ++f) ctx[f] = zero4;
    float mrun[4] = {-INFINITY, -INFINITY, -INFINITY, -INFINITY};
    float lrun[4] = {0.f, 0.f, 0.f, 0.f};

    for (int kt = 0; kt <= qt; ++kt) {
        const int k0 = kt * 64;
        __syncthreads();  // previous iter's ks/vs/ps reads done
        // stage K tile: 1024 chunks: r=key, c8=d-chunk; swizzle c8^(r&7)
#pragma unroll
        for (int j = 0; j < 4; ++j) {
            int chunk = tid + j * 256;
            int r = chunk >> 4, c8 = chunk & 15;
            *(uint4*)&ks[(r * 16 + (c8 ^ (r & 7))) * 8] =
                *(const uint4*)(Kk + (size_t)(b * S + k0 + r) * D + h * HDc + c8 * 8);
        }
        // stage V^T tile: dd=d-row, k8=key-chunk; swizzle k8^(dd&7)
#pragma unroll
        for (int j = 0; j < 4; ++j) {
            int chunk = tid + j * 256;
            int dd = chunk >> 3, k8 = chunk & 7;
            *(uint4*)&vs[(dd * 8 + (k8 ^ (dd & 7))) * 8] =
                *(const uint4*)(Vt + ((size_t)bh * HDc + dd) * S + k0 + k8 * 8);
        }
        __syncthreads();

        // S = Q @ K^T : sacc[kc] covers keys kc*16..+15
        f32x4 sacc[4];
#pragma unroll
        for (int kc = 0; kc < 4; ++kc) sacc[kc] = zero4;
#pragma unroll
        for (int kc = 0; kc < 4; ++kc) {
            const int krow = kc * 16 + l16;  // B-frag: col(key)=l16, k(d)=d4*32+lg*8
#pragma unroll
            for (int d4 = 0; d4 < 4; ++d4) {
                bf16x8 kf = *(const bf16x8*)&ks[(krow * 16 + ((d4 * 4 + lg) ^ (l16 & 7))) * 8];
                sacc[kc] = __builtin_amdgcn_mfma_f32_16x16x32_bf16(qf[d4], kf, sacc[kc], 0, 0, 0);
            }
        }

        // scale + causal mask. D-layout: row(q)=lg*4+r, col(key)=kc*16+l16
        float sv[4][4];
        const bool diag = (kt == qt);
#pragma unroll
        for (int kc = 0; kc < 4; ++kc)
#pragma unroll
            for (int r = 0; r < 4; ++r) {
                float s = sacc[kc][r] * scale;
                if (diag && (kc * 16 + l16) > (w * 16 + lg * 4 + r)) s = -INFINITY;
                sv[kc][r] = s;
            }

        // online softmax: reduce across the 16 lanes (cols) of each lg-group
        float alpha[4];
#pragma unroll
        for (int r = 0; r < 4; ++r) {
            float mx = fmaxf(fmaxf(sv[0][r], sv[1][r]), fmaxf(sv[2][r], sv[3][r]));
#pragma unroll
            for (int off = 1; off < 16; off <<= 1) mx = fmaxf(mx, __shfl_xor(mx, off));
            float mnew = fmaxf(mrun[r], mx);
            alpha[r] = (mrun[r] == -INFINITY) ? 0.f : __expf(mrun[r] - mnew);
            float psum = 0.f;
#pragma unroll
            for (int kc = 0; kc < 4; ++kc) {
                float p = __expf(sv[kc][r] - mnew);
                sv[kc][r] = p;
                psum += p;
            }
#pragma unroll
            for (int off = 1; off < 16; off <<= 1) psum += __shfl_xor(psum, off);
            lrun[r] = lrun[r] * alpha[r] + psum;
            mrun[r] = mnew;
        }
#pragma unroll
        for (int f = 0; f < 8; ++f) {
            ctx[f][0] *= alpha[0]; ctx[f][1] *= alpha[1];
            ctx[f][2] *= alpha[2]; ctx[f][3] *= alpha[3];
        }
        // P -> LDS (bf16), swizzled scalar writes
#pragma unroll
        for (int r = 0; r < 4; ++r) {
            int prow = lg * 4 + r;
#pragma unroll
            for (int kc = 0; kc < 4; ++kc)
                ps[w][prow * 64 + ((kc * 16 + l16) ^ ((prow & 7) << 3))] = (bf16_t)sv[kc][r];
        }
        __syncthreads();  // P visible (wave-local, but all waves are in lockstep loop)

        // ctx += P @ V : A-frag row=l16, k(key)=t*32+lg*8 ; B-frag col(d)=f*16+l16
#pragma unroll
        for (int t = 0; t < 2; ++t) {
            bf16x8 pa = *(const bf16x8*)&ps[w][l16 * 64 + ((t * 32 + lg * 8) ^ ((l16 & 7) << 3))];
#pragma unroll
            for (int f = 0; f < 8; ++f) {
                bf16x8 vb = *(const bf16x8*)&vs[((f * 16 + l16) * 8 + ((t * 4 + lg) ^ (l16 & 7))) * 8];
                ctx[f] = __builtin_amdgcn_mfma_f32_16x16x32_bf16(pa, vb, ctx[f], 0, 0, 0);
            }
        }
    }

    // epilogue: ctx/l -> bf16 [b*S+q][h*128+d]
    float invl[4];
#pragma unroll
    for (int r = 0; r < 4; ++r) invl[r] = 1.f / lrun[r];
#pragma unroll
    for (int f = 0; f < 8; ++f)
#pragma unroll
        for (int r = 0; r < 4; ++r) {
            int qrow = q0 + w * 16 + lg * 4 + r;
            Ctx[(size_t)(b * S + qrow) * D + h * HDc + f * 16 + l16] = (bf16_t)(ctx[f][r] * invl[r]);
        }
}

// ---------------------------------------------------------------------------
extern "C" void kernel_launch(void* const* d_in, const int* in_sizes, int n_in,
                              void* d_out, int out_size, void* d_ws, size_t ws_size,
                              hipStream_t stream) {
    const int B = 2, S = 2048, D = 2048, H = 16;
    const int M = B * S;  // 4096
    const float* x  = (const float*)d_in[0];
    const float* wq = (const float*)d_in[1];
    const float* wk = (const float*)d_in[2];
    const float* wv = (const float*)d_in[3];
    const float* wo = (const float*)d_in[4];
    const float* bo = (const float*)d_in[5];
    float* out = (float*)d_out;

    char* ws = (char*)d_ws;
    const size_t MB = 1024 * 1024;
    if (ws_size < 128 * MB) return;  // need 128MB scratch
    bf16_t* xb  = (bf16_t*)(ws);              // 16MB  x bf16
    bf16_t* wqb = (bf16_t*)(ws + 16 * MB);    // 8MB
    bf16_t* wkb = (bf16_t*)(ws + 24 * MB);
    bf16_t* wvb = (bf16_t*)(ws + 32 * MB);
    bf16_t* wob = (bf16_t*)(ws + 40 * MB);
    bf16_t* qb  = (bf16_t*)(ws + 48 * MB);    // 16MB each
    bf16_t* kb  = (bf16_t*)(ws + 64 * MB);
    bf16_t* vb  = (bf16_t*)(ws + 80 * MB);
    bf16_t* vtb = (bf16_t*)(ws + 96 * MB);
    bf16_t* cxb = (bf16_t*)(ws + 112 * MB);

    cvt_f32_to_bf16<<<M * D / 8 / 256, 256, 0, stream>>>(x, xb, M * D / 8);
    cvt_f32_to_bf16<<<D * D / 8 / 256, 256, 0, stream>>>(wq, wqb, D * D / 8);
    cvt_f32_to_bf16<<<D * D / 8 / 256, 256, 0, stream>>>(wk, wkb, D * D / 8);
    cvt_f32_to_bf16<<<D * D / 8 / 256, 256, 0, stream>>>(wv, wvb, D * D / 8);
    cvt_f32_to_bf16<<<D * D / 8 / 256, 256, 0, stream>>>(wo, wob, D * D / 8);

    gemm_qkv<<<dim3(M / 128, D / 128, 3), 256, 0, stream>>>(xb, wqb, wkb, wvb, qb, kb, vb, M, D, D);
    transpose_v<<<dim3(S / 64, D / 64, B), 256, 0, stream>>>(vb, vtb, S, H, B);
    attn_fwd<<<dim3(S / 64, B * H), 256, 0, stream>>>(qb, kb, vtb, cxb, B, S, H);
    gemm_bias_f32<<<dim3(M / 128, D / 128), 256, 0, stream>>>(cxb, wob, bo, out, M, D, D);
}

// Round 2
// 309.260 us; speedup vs baseline: 1.5426x; 1.5426x over previous
//
#include <hip/hip_runtime.h>
#include <math.h>

typedef __bf16 bf16_t;
typedef __bf16 bf16x8 __attribute__((ext_vector_type(8)));
typedef float f32x4 __attribute__((ext_vector_type(4)));

// async global->LDS, 16B per lane. Dest must be wave-uniform base; HW adds lane*16.
__device__ __forceinline__ void gload_lds16(const bf16_t* g, bf16_t* l) {
    __builtin_amdgcn_global_load_lds((const __attribute__((address_space(1))) void*)g,
                                     (__attribute__((address_space(3))) void*)l, 16, 0, 0);
}

// ---------------------------------------------------------------------------
// fp32 -> bf16 convert (vectorized 8/thread)
// ---------------------------------------------------------------------------
__global__ __launch_bounds__(256) void cvt_f32_to_bf16(const float* __restrict__ in,
                                                       bf16_t* __restrict__ out, int n8) {
    int i = blockIdx.x * 256 + threadIdx.x;
    if (i >= n8) return;
    const float4* p = (const float4*)in + (size_t)i * 2;
    float4 a = p[0], b = p[1];
    union { bf16_t h[8]; uint4 u; } pk;
    pk.h[0] = (bf16_t)a.x; pk.h[1] = (bf16_t)a.y; pk.h[2] = (bf16_t)a.z; pk.h[3] = (bf16_t)a.w;
    pk.h[4] = (bf16_t)b.x; pk.h[5] = (bf16_t)b.y; pk.h[6] = (bf16_t)b.z; pk.h[7] = (bf16_t)b.w;
    ((uint4*)out)[i] = pk.u;
}

// ---------------------------------------------------------------------------
// GEMM core: C[M,N] = A[M,K] @ B[N,K]^T (+bias). 128x128 tile, BK=32, 4 waves.
// global_load_lds staging (linear LDS) + 2-phase double-buffer, 1 barrier/K-step.
// ---------------------------------------------------------------------------
template <typename OutT>
__device__ __forceinline__ void gemm_core(const bf16_t* __restrict__ A,
                                          const bf16_t* __restrict__ Bm,
                                          const float* __restrict__ bias,
                                          OutT* __restrict__ C, int M, int N, int K) {
    __shared__ __align__(16) bf16_t As[2][128 * 32];
    __shared__ __align__(16) bf16_t Bs[2][128 * 32];
    const int tid = threadIdx.x;
    const int l = tid & 63, w = tid >> 6;
    const int l16 = l & 15, lg = l >> 4;
    const int wm = w >> 1, wn = w & 1;
    const int m0 = blockIdx.x * 128, n0 = blockIdx.y * 128;

    f32x4 acc[4][4] = {};

    const int r0 = tid >> 2, r1 = (tid + 256) >> 2, kc = tid & 3;  // chunk -> (row, kchunk)

    auto stageG = [&](int k0, int buf) {
        gload_lds16(A  + (size_t)(m0 + r0) * K + k0 + kc * 8, &As[buf][(w * 64) * 8]);
        gload_lds16(Bm + (size_t)(n0 + r0) * K + k0 + kc * 8, &Bs[buf][(w * 64) * 8]);
        gload_lds16(A  + (size_t)(m0 + r1) * K + k0 + kc * 8, &As[buf][(w * 64 + 256) * 8]);
        gload_lds16(Bm + (size_t)(n0 + r1) * K + k0 + kc * 8, &Bs[buf][(w * 64 + 256) * 8]);
    };

    int cur = 0;
    stageG(0, 0);
    const int nt = K / 32;
    for (int t = 0; t < nt; ++t) {
        __syncthreads();  // drains vmcnt+lgkmcnt: buf[cur] staged, prev reads done
        if (t + 1 < nt) stageG((t + 1) * 32, cur ^ 1);
        bf16x8 af[4], bfr[4];
#pragma unroll
        for (int i = 0; i < 4; ++i) {
            af[i]  = *(const bf16x8*)&As[cur][(wm * 64 + i * 16 + l16) * 32 + lg * 8];
            bfr[i] = *(const bf16x8*)&Bs[cur][(wn * 64 + i * 16 + l16) * 32 + lg * 8];
        }
#pragma unroll
        for (int mf = 0; mf < 4; ++mf)
#pragma unroll
            for (int nf = 0; nf < 4; ++nf)
                acc[mf][nf] = __builtin_amdgcn_mfma_f32_16x16x32_bf16(af[mf], bfr[nf], acc[mf][nf], 0, 0, 0);
        cur ^= 1;
    }
    // epilogue: C/D layout row=lg*4+r, col=l16
#pragma unroll
    for (int mf = 0; mf < 4; ++mf) {
#pragma unroll
        for (int nf = 0; nf < 4; ++nf) {
            int col = n0 + wn * 64 + nf * 16 + l16;
            float bv = bias ? bias[col] : 0.f;
#pragma unroll
            for (int r = 0; r < 4; ++r) {
                int row = m0 + wm * 64 + mf * 16 + lg * 4 + r;
                C[(size_t)row * N + col] = (OutT)(acc[mf][nf][r] + bv);
            }
        }
    }
}

__global__ __launch_bounds__(256) void gemm_qkv(const bf16_t* __restrict__ A,
                                                const bf16_t* __restrict__ W0,
                                                const bf16_t* __restrict__ W1,
                                                const bf16_t* __restrict__ W2,
                                                bf16_t* __restrict__ O0, bf16_t* __restrict__ O1,
                                                bf16_t* __restrict__ O2, int M, int N, int K) {
    const bf16_t* Bm = (blockIdx.z == 0) ? W0 : (blockIdx.z == 1) ? W1 : W2;
    bf16_t* C = (blockIdx.z == 0) ? O0 : (blockIdx.z == 1) ? O1 : O2;
    gemm_core<bf16_t>(A, Bm, nullptr, C, M, N, K);
}

__global__ __launch_bounds__(256) void gemm_bias_f32(const bf16_t* __restrict__ A,
                                                     const bf16_t* __restrict__ Bm,
                                                     const float* __restrict__ bias,
                                                     float* __restrict__ C, int M, int N, int K) {
    gemm_core<float>(A, Bm, bias, C, M, N, K);
}

// ---------------------------------------------------------------------------
// V transpose: [B*S, D] -> [B, H, 128, S]  (64x64 LDS tiles)
// ---------------------------------------------------------------------------
__global__ __launch_bounds__(256) void transpose_v(const bf16_t* __restrict__ V,
                                                   bf16_t* __restrict__ Vt, int S, int H, int Bn) {
    __shared__ bf16_t t[64][72];
    const int s0 = blockIdx.x * 64, d0 = blockIdx.y * 64, b = blockIdx.z;
    const int D = H * 128;
    const int tid = threadIdx.x;
#pragma unroll
    for (int j = 0; j < 2; ++j) {
        int chunk = tid + j * 256;
        int r = chunk >> 3, c8 = chunk & 7;
        *(uint4*)&t[r][c8 * 8] = *(const uint4*)(V + (size_t)(b * S + s0 + r) * D + d0 + c8 * 8);
    }
    __syncthreads();
#pragma unroll
    for (int j = 0; j < 2; ++j) {
        int chunk = tid + j * 256;
        int rr = chunk >> 3, cc = chunk & 7;
        union { bf16_t h[8]; uint4 u; } pk;
#pragma unroll
        for (int u = 0; u < 8; ++u) pk.h[u] = t[cc * 8 + u][rr];
        int dg = d0 + rr;
        size_t idx = ((size_t)(b * H + (dg >> 7)) * 128 + (dg & 127)) * S + s0 + cc * 8;
        *(uint4*)&Vt[idx] = pk.u;
    }
}

// ---------------------------------------------------------------------------
// Flash attention fwd, causal. 512 thr = 8 waves x 16 q-rows (Q-tile 128).
// Each block processes the balanced pair of q-tiles (p, 15-p): 36 K-iters each.
// K/V double-buffered via global_load_lds (pre-swizzled global source, linear
// LDS dest), 2-phase schedule: ONE barrier per K-tile, prefetch in flight.
// ---------------------------------------------------------------------------
__global__ __launch_bounds__(512) void attn_fwd(const bf16_t* __restrict__ Q,
                                                const bf16_t* __restrict__ Kk,
                                                const bf16_t* __restrict__ Vt,
                                                bf16_t* __restrict__ Ctx, int S, int H) {
    const int D = H * 128;
    const int p = blockIdx.x;   // 0..7
    const int bh = blockIdx.y;
    const int b = bh >> 4, h = bh & 15;
    const int tid = threadIdx.x;
    const int w = tid >> 6, l = tid & 63;
    const int l16 = l & 15, lg = l >> 4;

    __shared__ __align__(16) bf16_t ks[2][64 * 128];   // [key][d] chunks, XOR-swizzled
    __shared__ __align__(16) bf16_t vs[2][64 * 128];   // [d][key] chunks, XOR-swizzled
    __shared__ __align__(16) bf16_t ps[8][16 * 64];    // per-wave P, swizzled

    const float scale = 0.08838834764831845f;  // 1/sqrt(128)
    const f32x4 zero4 = {0.f, 0.f, 0.f, 0.f};

    // staging: 1024 16B-chunks per tile / 512 thr = 2 each. Chunk c holds logical
    // (r, c8 ^ (r&7)) so the LDS image is the swizzled layout with a LINEAR dest.
    auto stage = [&](int k0, int buf) {
#pragma unroll
        for (int j = 0; j < 2; ++j) {
            int c = tid + j * 512;
            int r = c >> 4;
            int c8 = (c & 15) ^ (r & 7);
            gload_lds16(Kk + (size_t)(b * S + k0 + r) * D + h * 128 + c8 * 8,
                        &ks[buf][(w * 64 + j * 512) * 8]);
            int dd = c >> 3;
            int k8 = (c & 7) ^ (dd & 7);
            gload_lds16(Vt + ((size_t)bh * 128 + dd) * S + k0 + k8 * 8,
                        &vs[buf][(w * 64 + j * 512) * 8]);
        }
    };

    for (int job = 0; job < 2; ++job) {
        const int qt = job ? (15 - p) : p;
        const int q0 = qt * 128;
        const int nkt = 2 * qt + 2;
        const int rmin = q0 + w * 16, rmax = rmin + 15;

        // Q A-frags: row=l16, k(d)=d4*32+lg*8
        bf16x8 qf[4];
        {
            const bf16_t* qp = Q + (size_t)(b * S + rmin + l16) * D + h * 128 + lg * 8;
#pragma unroll
            for (int d4 = 0; d4 < 4; ++d4) qf[d4] = *(const bf16x8*)(qp + d4 * 32);
        }
        f32x4 ctx[8];
#pragma unroll
        for (int f = 0; f < 8; ++f) ctx[f] = zero4;
        float mrun[4] = {-INFINITY, -INFINITY, -INFINITY, -INFINITY};
        float lrun[4] = {0.f, 0.f, 0.f, 0.f};

        __syncthreads();  // previous job's buffer readers done
        stage(0, 0);
        int cur = 0;
        for (int kt = 0; kt < nkt; ++kt) {
            __syncthreads();  // buf[cur] staged; prev iter's reads of buf[cur^1] done
            if (kt + 1 < nkt) stage((kt + 1) * 64, cur ^ 1);
            const int k0 = kt * 64;
            if (k0 <= rmax) {  // wave-uniform: skip fully-masked tiles
                // S = Q @ K^T
                f32x4 sacc[4];
#pragma unroll
                for (int kc = 0; kc < 4; ++kc) sacc[kc] = zero4;
#pragma unroll
                for (int kc = 0; kc < 4; ++kc) {
                    const int krow = kc * 16 + l16;
#pragma unroll
                    for (int d4 = 0; d4 < 4; ++d4) {
                        bf16x8 kf = *(const bf16x8*)&ks[cur][(krow * 16 + ((d4 * 4 + lg) ^ (krow & 7))) * 8];
                        sacc[kc] = __builtin_amdgcn_mfma_f32_16x16x32_bf16(qf[d4], kf, sacc[kc], 0, 0, 0);
                    }
                }
                // scale + causal mask (D-layout: row=lg*4+r, col=kc*16+l16)
                float sv[4][4];
                const bool needmask = (k0 + 63 > rmin);
#pragma unroll
                for (int kc = 0; kc < 4; ++kc)
#pragma unroll
                    for (int r = 0; r < 4; ++r) {
                        float s = sacc[kc][r] * scale;
                        if (needmask && (k0 + kc * 16 + l16) > (rmin + lg * 4 + r)) s = -INFINITY;
                        sv[kc][r] = s;
                    }
                // online softmax across 16 lanes per row
                float alpha[4];
#pragma unroll
                for (int r = 0; r < 4; ++r) {
                    float mx = fmaxf(fmaxf(sv[0][r], sv[1][r]), fmaxf(sv[2][r], sv[3][r]));
#pragma unroll
                    for (int off = 1; off < 16; off <<= 1) mx = fmaxf(mx, __shfl_xor(mx, off));
                    float mnew = fmaxf(mrun[r], mx);
                    alpha[r] = (mrun[r] == -INFINITY) ? 0.f : __expf(mrun[r] - mnew);
                    float psum = 0.f;
#pragma unroll
                    for (int kc = 0; kc < 4; ++kc) {
                        float pe = __expf(sv[kc][r] - mnew);
                        sv[kc][r] = pe;
                        psum += pe;
                    }
#pragma unroll
                    for (int off = 1; off < 16; off <<= 1) psum += __shfl_xor(psum, off);
                    lrun[r] = lrun[r] * alpha[r] + psum;
                    mrun[r] = mnew;
                }
#pragma unroll
                for (int f = 0; f < 8; ++f) {
                    ctx[f][0] *= alpha[0]; ctx[f][1] *= alpha[1];
                    ctx[f][2] *= alpha[2]; ctx[f][3] *= alpha[3];
                }
                // P -> per-wave LDS (no barrier needed: wave-private)
#pragma unroll
                for (int r = 0; r < 4; ++r) {
                    int prow = lg * 4 + r;
#pragma unroll
                    for (int kc = 0; kc < 4; ++kc)
                        ps[w][prow * 64 + ((kc * 16 + l16) ^ ((prow & 7) << 3))] = (bf16_t)sv[kc][r];
                }
                // ctx += P @ V
#pragma unroll
                for (int t = 0; t < 2; ++t) {
                    bf16x8 pa = *(const bf16x8*)&ps[w][l16 * 64 + ((t * 32 + lg * 8) ^ ((l16 & 7) << 3))];
#pragma unroll
                    for (int f = 0; f < 8; ++f) {
                        bf16x8 vb = *(const bf16x8*)&vs[cur][((f * 16 + l16) * 8 + ((t * 4 + lg) ^ (l16 & 7))) * 8];
                        ctx[f] = __builtin_amdgcn_mfma_f32_16x16x32_bf16(pa, vb, ctx[f], 0, 0, 0);
                    }
                }
            }
            cur ^= 1;
        }
        // epilogue for this q-tile
        float invl[4];
#pragma unroll
        for (int r = 0; r < 4; ++r) invl[r] = 1.f / lrun[r];
#pragma unroll
        for (int f = 0; f < 8; ++f)
#pragma unroll
            for (int r = 0; r < 4; ++r) {
                int qrow = rmin + lg * 4 + r;
                Ctx[(size_t)(b * S + qrow) * D + h * 128 + f * 16 + l16] = (bf16_t)(ctx[f][r] * invl[r]);
            }
    }
}

// ---------------------------------------------------------------------------
extern "C" void kernel_launch(void* const* d_in, const int* in_sizes, int n_in,
                              void* d_out, int out_size, void* d_ws, size_t ws_size,
                              hipStream_t stream) {
    const int B = 2, S = 2048, D = 2048, H = 16;
    const int M = B * S;  // 4096
    const float* x  = (const float*)d_in[0];
    const float* wq = (const float*)d_in[1];
    const float* wk = (const float*)d_in[2];
    const float* wv = (const float*)d_in[3];
    const float* wo = (const float*)d_in[4];
    const float* bo = (const float*)d_in[5];
    float* out = (float*)d_out;

    char* ws = (char*)d_ws;
    const size_t MB = 1024 * 1024;
    if (ws_size < 128 * MB) return;
    bf16_t* xb  = (bf16_t*)(ws);
    bf16_t* wqb = (bf16_t*)(ws + 16 * MB);
    bf16_t* wkb = (bf16_t*)(ws + 24 * MB);
    bf16_t* wvb = (bf16_t*)(ws + 32 * MB);
    bf16_t* wob = (bf16_t*)(ws + 40 * MB);
    bf16_t* qb  = (bf16_t*)(ws + 48 * MB);
    bf16_t* kb  = (bf16_t*)(ws + 64 * MB);
    bf16_t* vb  = (bf16_t*)(ws + 80 * MB);
    bf16_t* vtb = (bf16_t*)(ws + 96 * MB);
    bf16_t* cxb = (bf16_t*)(ws + 112 * MB);

    cvt_f32_to_bf16<<<M * D / 8 / 256, 256, 0, stream>>>(x, xb, M * D / 8);
    cvt_f32_to_bf16<<<D * D / 8 / 256, 256, 0, stream>>>(wq, wqb, D * D / 8);
    cvt_f32_to_bf16<<<D * D / 8 / 256, 256, 0, stream>>>(wk, wkb, D * D / 8);
    cvt_f32_to_bf16<<<D * D / 8 / 256, 256, 0, stream>>>(wv, wvb, D * D / 8);
    cvt_f32_to_bf16<<<D * D / 8 / 256, 256, 0, stream>>>(wo, wob, D * D / 8);

    gemm_qkv<<<dim3(M / 128, D / 128, 3), 256, 0, stream>>>(xb, wqb, wkb, wvb, qb, kb, vb, M, D, D);
    transpose_v<<<dim3(S / 64, D / 64, B), 256, 0, stream>>>(vb, vtb, S, H, B);
    attn_fwd<<<dim3(8, B * H), 512, 0, stream>>>(qb, kb, vtb, cxb, S, H);
    gemm_bias_f32<<<dim3(M / 128, D / 128), 256, 0, stream>>>(cxb, wob, bo, out, M, D, D);
}